// Round 1
// baseline (866.433 us; speedup 1.0000x reference)
//
#include <hip/hip_runtime.h>

// SpectralConv2d DHT pipeline, B=CIN=COUT=64, H=W=128, M1=M2=32.
// Everything is per flat channel ch in [0,4096): pure elementwise in ch.
//
// Pipeline per channel (all scales folded into tables):
//   A : CS[n1][j] = x(128x128) . T1(128x64)         (cos|sin over n2)
//       Xc[i][k2] = T2t^T(64x256) . stack(CS)       (cas/16384, i indexes K-set {0..31,96..127})
//   B1: hat = T4t^T . stack(tile . T3)              (DHT32 of Xc crops and of w1/w2 tiles)
//   B2: Y = T4t^T . stack((Ahat*What) . T3)         (scale 1/64 folded into T6)
//   C : UV[r][k2] = sum_j Y[j][k2]*T5t[j][r]        (r<128: cos p, r>=128: sin p)
//       out[p][q] = sum_ms UVt[ms][p]*T6[ms][q]     (T6 = cas*s4, s4 = 1/(64*16384*64))

#define OFF_T1   0        // [128][64]
#define OFF_T2T  8192     // [256][64]
#define OFF_T3   24576    // [32][64]
#define OFF_T4T  26624    // [64][32]
#define OFF_T5T  28672    // [64][256]
#define OFF_T6   45056    // [64][128]
#define OFF_XCY  53248    // [4096][64][32] (Xc, then Y in place)
#define WS_FLOATS (53248 + 4096 * 2048)

__device__ __forceinline__ int kmap(int i) { return (i < 32) ? i : 64 + i; }

__device__ __forceinline__ void fma4(float* a, float s, float4 b) {
    a[0] = fmaf(s, b.x, a[0]); a[1] = fmaf(s, b.y, a[1]);
    a[2] = fmaf(s, b.z, a[2]); a[3] = fmaf(s, b.w, a[3]);
}

__global__ __launch_bounds__(256) void init_tables(float* ws) {
    int idx = blockIdx.x * 256 + threadIdx.x;
    if (idx >= 53248) return;
    const float w128 = 6.2831853071795864769f / 128.0f;
    const float w32  = 6.2831853071795864769f / 32.0f;
    if (idx < 8192) {                       // T1[n2][j]: j<32 cos(2pi j n2/128) else sin
        int n2 = idx >> 6, j = idx & 63, jj = j & 31;
        float a = w128 * (float)((jj * n2) & 127);
        ws[OFF_T1 + idx] = (j < 32) ? cosf(a) : sinf(a);
    } else if (idx < 24576) {               // T2t[m][i]: m<128 cas(+K[i]m), else cas(-K[i](m-128)); /16384
        int t = idx - 8192, m = t >> 6, i = t & 63;
        int k1 = kmap(i);
        float v;
        if (m < 128) { float a = w128 * (float)((k1 * m) & 127); v = cosf(a) + sinf(a); }
        else { int mm = m - 128; float a = w128 * (float)((k1 * mm) & 127); v = cosf(a) - sinf(a); }
        ws[OFF_T2T + t] = v * (1.0f / 16384.0f);
    } else if (idx < 26624) {               // T3[n2][j]: j<32 cos(2pi j n2/32) else sin
        int t = idx - 24576, n2 = t >> 6, j = t & 63, jj = j & 31;
        float a = w32 * (float)((jj * n2) & 31);
        ws[OFF_T3 + t] = (j < 32) ? cosf(a) : sinf(a);
    } else if (idx < 28672) {               // T4t[m][k1]: m<32 cas(+k1 m), else cas(-k1(m-32)); /1024
        int t = idx - 26624, m = t >> 5, k1 = t & 31;
        float v;
        if (m < 32) { float a = w32 * (float)((k1 * m) & 31); v = cosf(a) + sinf(a); }
        else { int mm = m - 32; float a = w32 * (float)((k1 * mm) & 31); v = cosf(a) - sinf(a); }
        ws[OFF_T4T + t] = v * (1.0f / 1024.0f);
    } else if (idx < 45056) {               // T5t[j][r]: r<128 cos(2pi p K[j]/128) p=r, else sin p=r-128
        int t = idx - 28672, j = t >> 8, r = t & 255;
        int k1 = kmap(j);
        int p = (r < 128) ? r : r - 128;
        float a = w128 * (float)((p * k1) & 127);
        ws[OFF_T5T + t] = (r < 128) ? cosf(a) : sinf(a);
    } else {                                // T6[m][q]: m<32 cas(+q m), else cas(-q(m-32)); * s4
        int t = idx - 45056, m = t >> 7, q = t & 127;
        int k2 = m & 31;
        float a = w128 * (float)((q * k2) & 127);
        float c = cosf(a), s = sinf(a);
        const float s4 = 1.0f / 67108864.0f;  // (1/64 c-prefactor)*(1/16384 norm)*(1/64 final prefactor)
        ws[OFF_T6 + t] = ((m < 32) ? (c + s) : (c - s)) * s4;
    }
}

// ---------------- Kernel A: x -> Xc (per channel) ----------------
__global__ __launch_bounds__(256) void kA(const float* __restrict__ x, float* ws) {
    __shared__ float CS[8704];   // [128][68]
    __shared__ float BUF[6400];  // ph1: xT[32][132]@0 + T1c[32][68]@4224 ; ph2: T2c[64][64]@0
    const int tid = threadIdx.x;
    const int ch  = blockIdx.x;
    const float* xg = x + ch * 16384;

    // phase 1: CS[n1][j] = sum_n2 x[n1][n2] * T1[n2][j]
    const int j0 = (tid & 15) * 4;
    const int r0 = (tid >> 4) * 8;
    float acc[8][4];
#pragma unroll
    for (int i = 0; i < 8; i++) { acc[i][0] = acc[i][1] = acc[i][2] = acc[i][3] = 0.f; }

    for (int c = 0; c < 4; c++) {
#pragma unroll
        for (int i = 0; i < 16; i++) {    // x chunk, transposed: xT[n2][n1]
            int flat = i * 256 + tid;
            int n1 = flat >> 5, n2 = flat & 31;
            BUF[n2 * 132 + n1] = xg[n1 * 128 + c * 32 + n2];
        }
#pragma unroll
        for (int i = 0; i < 8; i++) {     // T1 rows chunk
            int flat = i * 256 + tid;
            int k = flat >> 6, j = flat & 63;
            BUF[4224 + k * 68 + j] = ws[OFF_T1 + (c * 32 + k) * 64 + j];
        }
        __syncthreads();
#pragma unroll 4
        for (int k = 0; k < 32; k++) {
            float4 b  = *(const float4*)&BUF[4224 + k * 68 + j0];
            float4 a0 = *(const float4*)&BUF[k * 132 + r0];
            float4 a1 = *(const float4*)&BUF[k * 132 + r0 + 4];
            fma4(acc[0], a0.x, b); fma4(acc[1], a0.y, b);
            fma4(acc[2], a0.z, b); fma4(acc[3], a0.w, b);
            fma4(acc[4], a1.x, b); fma4(acc[5], a1.y, b);
            fma4(acc[6], a1.z, b); fma4(acc[7], a1.w, b);
        }
        __syncthreads();
    }
#pragma unroll
    for (int i = 0; i < 8; i++)
        *(float4*)&CS[(r0 + i) * 68 + j0] =
            make_float4(acc[i][0], acc[i][1], acc[i][2], acc[i][3]);
    __syncthreads();

    // phase 2: Xc[i][k2] = sum_{m<256} T2t[m][i] * CSbig[m][k2]
    // CSbig[m][k2] = (m<128) ? CS[m][k2] : CS[m-128][32+k2]
    float a2[4][4];
#pragma unroll
    for (int i = 0; i < 4; i++) { a2[i][0] = a2[i][1] = a2[i][2] = a2[i][3] = 0.f; }
    const int i0  = (tid >> 3) * 4;   // valid for tid<128
    const int k20 = (tid & 7) * 4;
    for (int cm = 0; cm < 4; cm++) {
#pragma unroll
        for (int i = 0; i < 16; i++) {
            int flat = i * 256 + tid;
            BUF[flat] = ws[OFF_T2T + cm * 4096 + flat];
        }
        __syncthreads();
        if (tid < 128) {
            const int rowb = (cm & 1) * 64;
            const int colb = (cm < 2) ? k20 : (32 + k20);
#pragma unroll 4
            for (int ml = 0; ml < 64; ml++) {
                float4 av = *(const float4*)&BUF[ml * 64 + i0];
                float4 bv = *(const float4*)&CS[(rowb + ml) * 68 + colb];
                fma4(a2[0], av.x, bv); fma4(a2[1], av.y, bv);
                fma4(a2[2], av.z, bv); fma4(a2[3], av.w, bv);
            }
        }
        __syncthreads();
    }
    if (tid < 128) {
        float* xcg = ws + OFF_XCY + ch * 2048;
#pragma unroll
        for (int i = 0; i < 4; i++)
            *(float4*)&xcg[(i0 + i) * 32 + k20] =
                make_float4(a2[i][0], a2[i][1], a2[i][2], a2[i][3]);
    }
}

// ---------------- Kernel B1: DHT32 of all Xc crops and w tiles ----------------
__global__ __launch_bounds__(128) void kB1(const float* __restrict__ w1, const float* __restrict__ w2,
                                           float* ws, float* wh) {
    __shared__ float inT[2304];  // [2][32][36] transposed inputs
    __shared__ float G[4352];    // [2][32][68]
    __shared__ float T3c[2048];
    __shared__ float T4c[2048];
    const int tid = threadIdx.x;
#pragma unroll
    for (int i = 0; i < 16; i++) {
        int t = i * 128 + tid;
        T3c[t] = ws[OFF_T3 + t];
        T4c[t] = ws[OFF_T4T + t];
    }
    float* dstp[2];
#pragma unroll
    for (int tt = 0; tt < 2; tt++) {
        int g = blockIdx.x * 2 + tt;
        const float* src; float* dst;
        if (g < 8192) {                       // Xc crop tile (in-place)
            int ch = g >> 1, crop = g & 1;
            dst = ws + OFF_XCY + ch * 2048 + crop * 1024;
            src = dst;
        } else {                              // weight tile -> wh (in d_out scratch)
            int gw = g - 8192;
            int ch = gw >> 1, t2 = gw & 1;
            src = (t2 ? w2 : w1) + ch * 1024;
            dst = wh + gw * 1024;
        }
        dstp[tt] = dst;
#pragma unroll
        for (int i = 0; i < 8; i++) {
            int idx = i * 128 + tid;
            int rr = idx >> 5, cc = idx & 31;
            inT[tt * 1152 + cc * 36 + rr] = src[idx];
        }
    }
    __syncthreads();
    // stage i: G[tt][n1][j] = sum_k inT[tt][k][n1] * T3[k][j]
    {
        const int tt = tid >> 6, l = tid & 63;
        const int n10 = (l >> 4) * 8;
        const int jj0 = (l & 15) * 4;
        float ac[8][4];
#pragma unroll
        for (int i = 0; i < 8; i++) { ac[i][0] = ac[i][1] = ac[i][2] = ac[i][3] = 0.f; }
#pragma unroll 4
        for (int k = 0; k < 32; k++) {
            float4 b  = *(const float4*)&T3c[k * 64 + jj0];
            float4 a0 = *(const float4*)&inT[tt * 1152 + k * 36 + n10];
            float4 a1 = *(const float4*)&inT[tt * 1152 + k * 36 + n10 + 4];
            fma4(ac[0], a0.x, b); fma4(ac[1], a0.y, b);
            fma4(ac[2], a0.z, b); fma4(ac[3], a0.w, b);
            fma4(ac[4], a1.x, b); fma4(ac[5], a1.y, b);
            fma4(ac[6], a1.z, b); fma4(ac[7], a1.w, b);
        }
#pragma unroll
        for (int i = 0; i < 8; i++)
            *(float4*)&G[tt * 2176 + (n10 + i) * 68 + jj0] =
                make_float4(ac[i][0], ac[i][1], ac[i][2], ac[i][3]);
    }
    __syncthreads();
    // stage ii: hat[k1][k2] = sum_m T4t[m][k1] * G2[m][k2]
    {
        const int tt = tid >> 6, l = tid & 63;
        const int k10 = (l >> 3) * 4;
        const int k20 = (l & 7) * 4;
        float ac[4][4];
#pragma unroll
        for (int i = 0; i < 4; i++) { ac[i][0] = ac[i][1] = ac[i][2] = ac[i][3] = 0.f; }
#pragma unroll 4
        for (int m = 0; m < 64; m++) {
            float4 av = *(const float4*)&T4c[m * 32 + k10];
            const int row = m & 31;
            const int col = (m < 32) ? k20 : (32 + k20);
            float4 bv = *(const float4*)&G[tt * 2176 + row * 68 + col];
            fma4(ac[0], av.x, bv); fma4(ac[1], av.y, bv);
            fma4(ac[2], av.z, bv); fma4(ac[3], av.w, bv);
        }
        float* dst = dstp[tt];
#pragma unroll
        for (int i = 0; i < 4; i++)
            *(float4*)&dst[(k10 + i) * 32 + k20] =
                make_float4(ac[i][0], ac[i][1], ac[i][2], ac[i][3]);
    }
}

// ---------------- Kernel B2: Y = DHT32(Ahat*What) per channel ----------------
__global__ __launch_bounds__(128) void kB2(float* ws, const float* __restrict__ wh) {
    __shared__ float prodT[2304]; // [2][32][36]
    __shared__ float G[4352];
    __shared__ float T3c[2048];
    __shared__ float T4c[2048];
    const int tid = threadIdx.x;
    const int ch = blockIdx.x;
#pragma unroll
    for (int i = 0; i < 16; i++) {
        int t = i * 128 + tid;
        T3c[t] = ws[OFF_T3 + t];
        T4c[t] = ws[OFF_T4T + t];
    }
    float* xc = ws + OFF_XCY + ch * 2048;
    const float* whc = wh + ch * 2048;
#pragma unroll
    for (int i = 0; i < 16; i++) {
        int flat = i * 128 + tid;
        int c = flat >> 10, r = (flat >> 5) & 31, cc = flat & 31;
        prodT[c * 1152 + cc * 36 + r] = xc[flat] * whc[flat];
    }
    __syncthreads();
    {   // stage i
        const int tt = tid >> 6, l = tid & 63;
        const int n10 = (l >> 4) * 8;
        const int jj0 = (l & 15) * 4;
        float ac[8][4];
#pragma unroll
        for (int i = 0; i < 8; i++) { ac[i][0] = ac[i][1] = ac[i][2] = ac[i][3] = 0.f; }
#pragma unroll 4
        for (int k = 0; k < 32; k++) {
            float4 b  = *(const float4*)&T3c[k * 64 + jj0];
            float4 a0 = *(const float4*)&prodT[tt * 1152 + k * 36 + n10];
            float4 a1 = *(const float4*)&prodT[tt * 1152 + k * 36 + n10 + 4];
            fma4(ac[0], a0.x, b); fma4(ac[1], a0.y, b);
            fma4(ac[2], a0.z, b); fma4(ac[3], a0.w, b);
            fma4(ac[4], a1.x, b); fma4(ac[5], a1.y, b);
            fma4(ac[6], a1.z, b); fma4(ac[7], a1.w, b);
        }
#pragma unroll
        for (int i = 0; i < 8; i++)
            *(float4*)&G[tt * 2176 + (n10 + i) * 68 + jj0] =
                make_float4(ac[i][0], ac[i][1], ac[i][2], ac[i][3]);
    }
    __syncthreads();
    {   // stage ii -> Y in place over Xc
        const int tt = tid >> 6, l = tid & 63;
        const int k10 = (l >> 3) * 4;
        const int k20 = (l & 7) * 4;
        float ac[4][4];
#pragma unroll
        for (int i = 0; i < 4; i++) { ac[i][0] = ac[i][1] = ac[i][2] = ac[i][3] = 0.f; }
#pragma unroll 4
        for (int m = 0; m < 64; m++) {
            float4 av = *(const float4*)&T4c[m * 32 + k10];
            const int row = m & 31;
            const int col = (m < 32) ? k20 : (32 + k20);
            float4 bv = *(const float4*)&G[tt * 2176 + row * 68 + col];
            fma4(ac[0], av.x, bv); fma4(ac[1], av.y, bv);
            fma4(ac[2], av.z, bv); fma4(ac[3], av.w, bv);
        }
        float* dst = xc + tt * 1024;
#pragma unroll
        for (int i = 0; i < 4; i++)
            *(float4*)&dst[(k10 + i) * 32 + k20] =
                make_float4(ac[i][0], ac[i][1], ac[i][2], ac[i][3]);
    }
}

// ---------------- Kernel C: Y -> out (per channel) ----------------
__global__ __launch_bounds__(256) void kC(float* __restrict__ out, const float* ws) {
    __shared__ float Yl[2304];   // [64][36]
    __shared__ float TC[4352];   // [64][68]: T5 chunks, then T6 halves
    __shared__ float UVt[8448];  // [64][132]: ms = k2 (U) / 32+k2 (V), cols p
    const int tid = threadIdx.x;
    const int ch = blockIdx.x;
    const float* yg = ws + OFF_XCY + ch * 2048;
#pragma unroll
    for (int i = 0; i < 8; i++) {
        int flat = i * 256 + tid;
        int j = flat >> 5, k2 = flat & 31;
        Yl[j * 36 + k2] = yg[flat];
    }
    // stage 1: UV[r][k2] = sum_j Y[j][k2] * T5t[j][r]  (4 chunks of 64 r)
    for (int rc = 0; rc < 4; rc++) {
#pragma unroll
        for (int i = 0; i < 16; i++) {
            int flat = i * 256 + tid;
            int j = flat >> 6, rl = flat & 63;
            TC[j * 68 + rl] = ws[OFF_T5T + j * 256 + rc * 64 + rl];
        }
        __syncthreads();
        if (tid < 128) {
            const int rr0 = (tid >> 3) * 4;
            const int k20 = (tid & 7) * 4;
            float ac[4][4];
#pragma unroll
            for (int i = 0; i < 4; i++) { ac[i][0] = ac[i][1] = ac[i][2] = ac[i][3] = 0.f; }
#pragma unroll 4
            for (int j = 0; j < 64; j++) {
                float4 av = *(const float4*)&TC[j * 68 + rr0];
                float4 bv = *(const float4*)&Yl[j * 36 + k20];
                fma4(ac[0], av.x, bv); fma4(ac[1], av.y, bv);
                fma4(ac[2], av.z, bv); fma4(ac[3], av.w, bv);
            }
            const int msb = (rc < 2) ? k20 : (32 + k20);
            const int p = (rc * 64 + rr0) & 127;
#pragma unroll
            for (int ri = 0; ri < 4; ri++)
#pragma unroll
                for (int ki = 0; ki < 4; ki++)
                    UVt[(msb + ki) * 132 + p + ri] = ac[ri][ki];
        }
        __syncthreads();
    }
    // stage 2: out[p][q] = sum_ms UVt[ms][p] * T6[ms][q]  (2 q-halves)
    for (int qh = 0; qh < 2; qh++) {
#pragma unroll
        for (int i = 0; i < 16; i++) {
            int flat = i * 256 + tid;
            int m = flat >> 6, ql = flat & 63;
            TC[m * 68 + ql] = ws[OFF_T6 + m * 128 + qh * 64 + ql];
        }
        __syncthreads();
        const int p0 = (tid >> 4) * 8;
        const int q0 = (tid & 15) * 4;
        float ac[8][4];
#pragma unroll
        for (int i = 0; i < 8; i++) { ac[i][0] = ac[i][1] = ac[i][2] = ac[i][3] = 0.f; }
#pragma unroll 4
        for (int m = 0; m < 64; m++) {
            float4 b  = *(const float4*)&TC[m * 68 + q0];
            float4 a0 = *(const float4*)&UVt[m * 132 + p0];
            float4 a1 = *(const float4*)&UVt[m * 132 + p0 + 4];
            fma4(ac[0], a0.x, b); fma4(ac[1], a0.y, b);
            fma4(ac[2], a0.z, b); fma4(ac[3], a0.w, b);
            fma4(ac[4], a1.x, b); fma4(ac[5], a1.y, b);
            fma4(ac[6], a1.z, b); fma4(ac[7], a1.w, b);
        }
#pragma unroll
        for (int i = 0; i < 8; i++)
            *(float4*)&out[ch * 16384 + (p0 + i) * 128 + qh * 64 + q0] =
                make_float4(ac[i][0], ac[i][1], ac[i][2], ac[i][3]);
        __syncthreads();
    }
}

extern "C" void kernel_launch(void* const* d_in, const int* in_sizes, int n_in,
                              void* d_out, int out_size, void* d_ws, size_t ws_size,
                              hipStream_t stream) {
    (void)in_sizes; (void)n_in; (void)out_size;
    if (ws_size < (size_t)WS_FLOATS * sizeof(float)) return;  // need ~33.8 MB scratch
    const float* x  = (const float*)d_in[0];
    const float* w1 = (const float*)d_in[1];
    const float* w2 = (const float*)d_in[2];
    float* out = (float*)d_out;
    float* ws  = (float*)d_ws;
    float* wh  = out;  // What scratch lives in d_out (33.5 MB), fully overwritten by kC later

    hipLaunchKernelGGL(init_tables, dim3(208), dim3(256), 0, stream, ws);
    hipLaunchKernelGGL(kA,  dim3(4096), dim3(256), 0, stream, x, ws);
    hipLaunchKernelGGL(kB1, dim3(8192), dim3(128), 0, stream, w1, w2, ws, wh);
    hipLaunchKernelGGL(kB2, dim3(4096), dim3(128), 0, stream, ws, wh);
    hipLaunchKernelGGL(kC,  dim3(4096), dim3(256), 0, stream, out, ws);
}